// Round 9
// baseline (251.477 us; speedup 1.0000x reference)
//
#include <hip/hip_runtime.h>
#include <stdint.h>

#define NL 2048
#define ND 256
#define KVB 32
#define QB 128
#define NQT 16                      // 128-row q-tiles per batch
#define NT_ALL (NL / KVB)           // 64 kv tiles per batch
#define CHUNK 8                     // kv tiles per block
#define NCHUNKS_B 79                // 8 (qt=0 full span) + sum_{qt=1..15} ceil((4qt+4)/8)
#define TILE_BYTES (KVB * ND * 2)   // 16 KB LDS image per kv tile
#define IMG (8 * NT_ALL * TILE_BYTES)
#define WS_K 256
#define WS_V (WS_K + IMG)
#define WS_Q (WS_V + IMG)
#define WS_P (WS_Q + IMG)
#define PART_BYTES (QB * ND * 2 + QB * 8)  // bf16 acc + fp32 m,l = 66560

typedef __attribute__((ext_vector_type(8))) short short8;
typedef __attribute__((ext_vector_type(4))) short short4v;
typedef __attribute__((ext_vector_type(4))) float f32x4;
typedef __attribute__((ext_vector_type(8))) unsigned short ushort8;

__device__ __forceinline__ unsigned short bf16rne(float x) {
  unsigned u = __builtin_bit_cast(unsigned, x);
  u += 0x7FFFu + ((u >> 16) & 1u);
  return (unsigned short)(u >> 16);
}

__device__ __forceinline__ short8 cvt8(float4 a, float4 b, float scale) {
  short8 v;
  v[0] = (short)bf16rne(a.x * scale);
  v[1] = (short)bf16rne(a.y * scale);
  v[2] = (short)bf16rne(a.z * scale);
  v[3] = (short)bf16rne(a.w * scale);
  v[4] = (short)bf16rne(b.x * scale);
  v[5] = (short)bf16rne(b.y * scale);
  v[6] = (short)bf16rne(b.z * scale);
  v[7] = (short)bf16rne(b.w * scale);
  return v;
}

// Mask storage probe: any word not 0/1 in the first 4096 words => byte bools.
__global__ void mask_mode_kernel(const unsigned* __restrict__ M, int* __restrict__ flag) {
  bool bad = false;
  for (int i = threadIdx.x; i < 4096; i += 64) {
    if (M[i] > 1u) bad = true;
  }
  unsigned long long b = __ballot(bad);
  if (threadIdx.x == 0) *flag = (b != 0ULL) ? 1 : 0;
}

// One-shot Q,K,V fp32->bf16 conversion. K stored as XOR-swizzled LDS tile
// images, V in the tr-read subtile layout, Q row-major with 1/16 pre-applied.
__global__ __launch_bounds__(128)
void convert_qkv(const float* __restrict__ Q, const float* __restrict__ K,
                 const float* __restrict__ V, unsigned char* __restrict__ ws) {
  const int t = blockIdx.x;  // b*64 + tix  (32-row groups)
  const int b = t >> 6, tix = t & 63;
  const float* qt = Q + ((size_t)b * NL + tix * KVB) * ND;
  const float* kt = K + ((size_t)b * NL + tix * KVB) * ND;
  const float* vt = V + ((size_t)b * NL + tix * KVB) * ND;
  unsigned char* qd = ws + WS_Q + (size_t)t * TILE_BYTES;
  unsigned char* kd = ws + WS_K + (size_t)t * TILE_BYTES;
  unsigned char* vd = ws + WS_V + (size_t)t * TILE_BYTES;
#pragma unroll
  for (int it = 0; it < 8; ++it) {
    int idx = it * 128 + threadIdx.x;
    int row = idx >> 5, u = idx & 31, f = u * 8;
    const float4* qp = (const float4*)(qt + (size_t)row * ND + f);
    *(short8*)(qd + (row * 512 + f * 2)) = cvt8(qp[0], qp[1], 0.0625f);
    const float4* kp = (const float4*)(kt + (size_t)row * ND + f);
    int kb = (row * 512 + f * 2) ^ ((row & 7) << 4);
    *(short8*)(kd + kb) = cvt8(kp[0], kp[1], 1.0f);
    const float4* vp = (const float4*)(vt + (size_t)row * ND + f);
    int vb = (row >> 2) * 2048 + (u >> 1) * 128 + (row & 3) * 32 + (u & 1) * 16;
    *(short8*)(vd + vb) = cvt8(vp[0], vp[1], 1.0f);
  }
}

// Flash attention fwd: block = (b, 128-row q-tile, chunk of <=8 kv tiles),
// 8 waves, double-buffered global_load_lds DMA, 1 barrier/tile. qt=0 spans
// ALL 64 kv tiles so the LSE combine reproduces the reference's -10000-tier
// tie semantics exactly. Natural dispatch order (r8's XCD affinity refuted).
__global__ __launch_bounds__(512, 4)
void attn_fwd(const int* __restrict__ Mg, unsigned char* ws,
              const int* __restrict__ modeFlag) {
  __shared__ unsigned short Ks[2][KVB * ND];   // 32 KB (also epilogue scratch)
  __shared__ unsigned short Vs[2][KVB * ND];   // 32 KB
  __shared__ unsigned short Ps[8][16 * KVB];   // per-wave P (8 KB)
  __shared__ float biasC[CHUNK * KVB];         // whole-chunk padding bias (1 KB)

  const int tid = threadIdx.x;
  const int wv = tid >> 6;      // wave 0..7
  const int lane = tid & 63;
  const int g = lane >> 4;      // 4-lane-group id
  const int cc = lane & 15;     // lane-in-group
  const int maskByteMode = *modeFlag;

  // ---- decode fid -> (b, qt, c)
  const int fid = blockIdx.x;
  const int b = fid / NCHUNKS_B;
  int rem = fid - b * NCHUNKS_B;
  int qt = 0, c = 0, pbase = 0;
  if (rem < 8) {
    qt = 0; c = rem; pbase = 0;
  } else {
    rem -= 8; pbase = 8;
    for (qt = 1; qt < NQT; ++qt) {
      int ncq = (4 * qt + 4 + CHUNK - 1) / CHUNK;
      if (rem < ncq) { c = rem; break; }
      rem -= ncq; pbase += ncq;
    }
  }
  const int qb = qt * QB;
  const int nt_s = (qt == 0) ? NT_ALL : (4 * qt + 4);
  const int t0 = c * CHUNK;
  const int t1 = min(nt_s, t0 + CHUNK);
  unsigned char* pp = ws + WS_P + (size_t)(b * NCHUNKS_B + pbase + c) * PART_BYTES;
  unsigned short* ppA = (unsigned short*)pp;
  float* ppM = (float*)(pp + QB * ND * 2);
  float* ppL = ppM + QB;

  // ---- hoist padding-mask bias for the whole chunk out of the tile chain
  {
    int nb = (t1 - t0) * KVB;
    for (int i = tid; i < nb; i += 512) {
      size_t gi = (size_t)b * NL + t0 * KVB + i;
      int mv = maskByteMode ? (int)((const unsigned char*)Mg)[gi] : Mg[gi];
      biasC[i] = mv ? 0.f : -10000.f;
    }
  }

  auto stage_tile = [&](int tix, int bi) {
    const unsigned char* kg = ws + WS_K + ((size_t)(b * NT_ALL + tix)) * TILE_BYTES;
    const unsigned char* vg = ws + WS_V + ((size_t)(b * NT_ALL + tix)) * TILE_BYTES;
#pragma unroll
    for (int s = 0; s < 2; ++s) {
      const int seg = wv * 2 + s;  // wave-uniform LDS dest; per-lane global src
      __builtin_amdgcn_global_load_lds(
          (const __attribute__((address_space(1))) unsigned int*)(kg + seg * 1024 + lane * 16),
          (__attribute__((address_space(3))) unsigned int*)((unsigned char*)&Ks[bi][0] + seg * 1024),
          16, 0, 0);
      __builtin_amdgcn_global_load_lds(
          (const __attribute__((address_space(1))) unsigned int*)(vg + seg * 1024 + lane * 16),
          (__attribute__((address_space(3))) unsigned int*)((unsigned char*)&Vs[bi][0] + seg * 1024),
          16, 0, 0);
    }
  };

  // ---- Q fragments from bf16 image (1/16 pre-applied): row qb+16wv+cc
  const unsigned char* qrow = ws + WS_Q + ((size_t)b * NL + (qb + 16 * wv + cc)) * 512;
  short8 qf[8];
#pragma unroll
  for (int ch = 0; ch < 8; ++ch) {
    qf[ch] = *(const short8*)(qrow + ch * 64 + g * 16);
  }

  f32x4 acc[16];
#pragma unroll
  for (int i = 0; i < 16; ++i) acc[i] = (f32x4){0.f, 0.f, 0.f, 0.f};
  float m_run[4], l_run[4];
#pragma unroll
  for (int r = 0; r < 4; ++r) { m_run[r] = -3.0e38f; l_run[r] = 0.f; }

  int buf = 0;
  stage_tile(t0, 0);
  __syncthreads();  // drains DMA + biasC writes

  for (int tix = t0; tix < t1; ++tix) {
    if (tix + 1 < t1) stage_tile(tix + 1, buf ^ 1);  // DMA under this compute
    const int kv0 = tix * KVB;
    const float* biasT = &biasC[(tix - t0) * KVB];

    // ---- S = Q K^T (two 16-col kv tiles)
    const char* ksB = (const char*)&Ks[buf][0];
    f32x4 s0 = {0.f, 0.f, 0.f, 0.f}, s1 = {0.f, 0.f, 0.f, 0.f};
#pragma unroll
    for (int ch = 0; ch < 8; ++ch) {
      int cbase = ch * 64 + g * 16;
      int b0 = (cc * 512 + cbase) ^ ((cc & 7) << 4);
      int b1 = ((cc + 16) * 512 + cbase) ^ ((cc & 7) << 4);
      short8 k0 = *reinterpret_cast<const short8*>(ksB + b0);
      short8 k1 = *reinterpret_cast<const short8*>(ksB + b1);
      s0 = __builtin_amdgcn_mfma_f32_16x16x32_bf16(qf[ch], k0, s0, 0, 0, 0);
      s1 = __builtin_amdgcn_mfma_f32_16x16x32_bf16(qf[ch], k1, s1, 0, 0, 0);
    }
    // ---- biases: padding (all rows), causal (diagonal tiles and beyond)
    float bi0 = biasT[cc], bi1 = biasT[16 + cc];
    s0 += bi0;
    s1 += bi1;
    if (kv0 + KVB - 1 > qb) {
      int kvg0 = kv0 + cc, kvg1 = kv0 + 16 + cc;
      int qg = qb + 16 * wv + 4 * g;
#pragma unroll
      for (int r = 0; r < 4; ++r) {
        if (kvg0 > qg + r) s0[r] -= 10000.f;
        if (kvg1 > qg + r) s1[r] -= 10000.f;
      }
    }
    // ---- online softmax (row 4g+r lives in the 16 lanes sharing g)
    float rmax[4], alpha[4], rsum[4];
#pragma unroll
    for (int r = 0; r < 4; ++r) rmax[r] = fmaxf(s0[r], s1[r]);
#pragma unroll
    for (int off = 8; off >= 1; off >>= 1) {
#pragma unroll
      for (int r = 0; r < 4; ++r) rmax[r] = fmaxf(rmax[r], __shfl_xor(rmax[r], off));
    }
#pragma unroll
    for (int r = 0; r < 4; ++r) {
      float mn = fmaxf(m_run[r], rmax[r]);
      alpha[r] = __expf(m_run[r] - mn);
      m_run[r] = mn;
    }
#pragma unroll
    for (int r = 0; r < 4; ++r) {
      s0[r] = __expf(s0[r] - m_run[r]);
      s1[r] = __expf(s1[r] - m_run[r]);
      rsum[r] = s0[r] + s1[r];
    }
#pragma unroll
    for (int off = 8; off >= 1; off >>= 1) {
#pragma unroll
      for (int r = 0; r < 4; ++r) rsum[r] += __shfl_xor(rsum[r], off);
    }
    f32x4 av = {alpha[0], alpha[1], alpha[2], alpha[3]};
#pragma unroll
    for (int r = 0; r < 4; ++r) l_run[r] = l_run[r] * alpha[r] + rsum[r];
#pragma unroll
    for (int i = 0; i < 16; ++i) acc[i] *= av;

    // ---- P -> per-wave LDS so PV's A-operand reads contiguous kv
    unsigned short* pw = &Ps[wv][0];
#pragma unroll
    for (int r = 0; r < 4; ++r) {
      pw[(4 * g + r) * KVB + cc] = bf16rne(s0[r]);
      pw[(4 * g + r) * KVB + 16 + cc] = bf16rne(s1[r]);
    }
    asm volatile("s_waitcnt lgkmcnt(0)" ::: "memory");
    short8 pa = *reinterpret_cast<const short8*>((const char*)pw + cc * 64 + g * 16);

    // ---- O += P V via hardware transpose reads (8 B/lane natural addressing)
    const unsigned va = (unsigned)(uintptr_t)&Vs[buf][0] + g * 4096 + cc * 8;
#pragma unroll
    for (int h8 = 0; h8 < 2; ++h8) {
      short4v lo[8], hi[8];
#pragma unroll
      for (int f8 = 0; f8 < 8; ++f8) {
        const int ft = h8 * 8 + f8;
        asm volatile("ds_read_b64_tr_b16 %0, %1 offset:%2"
                     : "=&v"(lo[f8]) : "v"(va), "i"(ft * 128) : "memory");
        asm volatile("ds_read_b64_tr_b16 %0, %1 offset:%2"
                     : "=&v"(hi[f8]) : "v"(va), "i"(ft * 128 + 2048) : "memory");
      }
      asm volatile("s_waitcnt lgkmcnt(0)" ::: "memory");
      __builtin_amdgcn_sched_barrier(0);
#pragma unroll
      for (int f8 = 0; f8 < 8; ++f8) {
        short8 vb = __builtin_shufflevector(lo[f8], hi[f8], 0, 1, 2, 3, 4, 5, 6, 7);
        acc[h8 * 8 + f8] =
            __builtin_amdgcn_mfma_f32_16x16x32_bf16(pa, vb, acc[h8 * 8 + f8], 0, 0, 0);
      }
    }

    __syncthreads();  // drains prefetch DMA + releases buf
    buf ^= 1;
  }

  // ---- partial epilogue: m,l then acc via 2 half-passes through 32 KB scratch
  if (cc == 0) {
#pragma unroll
    for (int r = 0; r < 4; ++r) {
      int rr = 16 * wv + 4 * g + r;
      ppM[rr] = m_run[r];
      ppL[rr] = l_run[r];
    }
  }
  unsigned short* sc = &Ks[0][0];  // contiguous 32 KB = 64 rows x 256 cols
#pragma unroll
  for (int h = 0; h < 2; ++h) {
    __syncthreads();
    if ((wv >> 2) == h) {
#pragma unroll
      for (int ft = 0; ft < 16; ++ft) {
#pragma unroll
        for (int r = 0; r < 4; ++r) {
          sc[(16 * (wv & 3) + 4 * g + r) * 256 + ft * 16 + cc] = bf16rne(acc[ft][r]);
        }
      }
    }
    __syncthreads();
    const int row = tid >> 3, oct = tid & 7;
    const ushort8* src = (const ushort8*)(sc + row * 256 + oct * 32);
    ushort8* dst = (ushort8*)(ppA + (size_t)(h * 64 + row) * ND + oct * 32);
#pragma unroll
    for (int k = 0; k < 4; ++k) __builtin_nontemporal_store(src[k], dst + k);
  }
}

// Exact log-sum-exp merge of the variable-count partials per (b, q-tile, half).
__global__ __launch_bounds__(256)
void attn_combine(const unsigned char* __restrict__ ws, float* __restrict__ Og) {
  const int bid = blockIdx.x;  // b(3) | qt(4) | half(1)
  const int b = bid >> 5;
  const int qt = (bid >> 1) & 15;
  const int h = bid & 1;
  const int tid = threadIdx.x;
  const int row = tid >> 2, sub = tid & 3;
  const int grow = h * 64 + row;

  int pbase = 0, nc = 8;
  if (qt > 0) {
    pbase = 8;
    for (int j = 1; j < qt; ++j) pbase += (4 * j + 4 + CHUNK - 1) / CHUNK;
    nc = (4 * qt + 4 + CHUNK - 1) / CHUNK;
  }
  const unsigned char* p0 = ws + WS_P + (size_t)(b * NCHUNKS_B + pbase) * PART_BYTES;

  float M = -3.0e38f;
  for (int c = 0; c < nc; ++c) {
    M = fmaxf(M, *(const float*)(p0 + (size_t)c * PART_BYTES + QB * ND * 2 + grow * 4));
  }
  float L = 0.f;
  float o[64];
#pragma unroll
  for (int j = 0; j < 64; ++j) o[j] = 0.f;
  for (int c = 0; c < nc; ++c) {
    const unsigned char* pc = p0 + (size_t)c * PART_BYTES;
    float mm = *(const float*)(pc + QB * ND * 2 + grow * 4);
    float ll = *(const float*)(pc + QB * ND * 2 + QB * 4 + grow * 4);
    float s = __expf(mm - M);
    L += ll * s;
    const ushort8* pa = (const ushort8*)((const unsigned short*)pc +
                                         (size_t)grow * ND + sub * 64);
#pragma unroll
    for (int kk = 0; kk < 8; ++kk) {
      ushort8 a = __builtin_nontemporal_load(pa + kk);
#pragma unroll
      for (int j = 0; j < 8; ++j) {
        unsigned u = ((unsigned)a[j]) << 16;
        o[kk * 8 + j] += __builtin_bit_cast(float, u) * s;
      }
    }
  }
  const float invL = 1.0f / L;
  float* op = Og + ((size_t)b * NL + qt * QB + grow) * ND + sub * 64;
#pragma unroll
  for (int kk = 0; kk < 16; ++kk) {
    float4 v = {o[kk * 4] * invL, o[kk * 4 + 1] * invL, o[kk * 4 + 2] * invL,
                o[kk * 4 + 3] * invL};
    *(float4*)(op + kk * 4) = v;
  }
}

extern "C" void kernel_launch(void* const* d_in, const int* in_sizes, int n_in,
                              void* d_out, int out_size, void* d_ws, size_t ws_size,
                              hipStream_t stream) {
  (void)in_sizes; (void)n_in; (void)out_size; (void)ws_size;  // need 67.2MB <= 67.6MB proven (r5)
  const float* Q = (const float*)d_in[0];
  const float* K = (const float*)d_in[1];
  const float* V = (const float*)d_in[2];
  const int* M = (const int*)d_in[3];
  unsigned char* ws = (unsigned char*)d_ws;

  mask_mode_kernel<<<dim3(1), dim3(64), 0, stream>>>((const unsigned*)M, (int*)ws);
  convert_qkv<<<dim3(512), dim3(128), 0, stream>>>(Q, K, V, ws);
  attn_fwd<<<dim3(8 * NCHUNKS_B), dim3(512), 0, stream>>>(M, ws, (const int*)ws);
  attn_combine<<<dim3(256), dim3(256), 0, stream>>>(ws, (float*)d_out);
}

// Round 10
// 141.015 us; speedup vs baseline: 1.7833x; 1.7833x over previous
//
#include <hip/hip_runtime.h>
#include <stdint.h>

#define NL 2048
#define ND 256
#define KVB 32
#define QB 64
#define NQT 32                      // 64-row q-tiles per batch
#define NT_ALL (NL / KVB)           // 64 kv tiles per batch
#define CHUNK 8                     // kv tiles per block (balanced schedule)
#define NCHUNKS_B 151               // 8 (qt=0 full span) + sum_{qt=1..31}(qt/4+1)
#define TILE_BYTES (KVB * ND * 2)   // 16 KB image per kv tile
#define IMG (8 * NT_ALL * TILE_BYTES)
#define WS_K 256
#define WS_V (WS_K + IMG)
#define WS_Q (WS_V + IMG)
#define WS_P (WS_Q + IMG)
#define PART_BYTES (QB * ND * 2 + QB * 8)  // bf16 acc + fp32 m,l = 33280

typedef __attribute__((ext_vector_type(8))) short short8;
typedef __attribute__((ext_vector_type(4))) short short4v;
typedef __attribute__((ext_vector_type(4))) float f32x4;
typedef __attribute__((ext_vector_type(8))) unsigned short ushort8;

__device__ __forceinline__ unsigned short bf16rne(float x) {
  unsigned u = __builtin_bit_cast(unsigned, x);
  u += 0x7FFFu + ((u >> 16) & 1u);
  return (unsigned short)(u >> 16);
}

__device__ __forceinline__ short8 cvt8(float4 a, float4 b, float scale) {
  short8 v;
  v[0] = (short)bf16rne(a.x * scale);
  v[1] = (short)bf16rne(a.y * scale);
  v[2] = (short)bf16rne(a.z * scale);
  v[3] = (short)bf16rne(a.w * scale);
  v[4] = (short)bf16rne(b.x * scale);
  v[5] = (short)bf16rne(b.y * scale);
  v[6] = (short)bf16rne(b.z * scale);
  v[7] = (short)bf16rne(b.w * scale);
  return v;
}

// Mask storage probe: any word not 0/1 in the first 4096 words => byte bools.
__global__ void mask_mode_kernel(const unsigned* __restrict__ M, int* __restrict__ flag) {
  bool bad = false;
  for (int i = threadIdx.x; i < 4096; i += 64) {
    if (M[i] > 1u) bad = true;
  }
  unsigned long long b = __ballot(bad);
  if (threadIdx.x == 0) *flag = (b != 0ULL) ? 1 : 0;
}

// One-shot Q,K,V fp32->bf16 conversion. K stored as XOR-swizzled LDS tile
// images, V in the tr-read subtile layout, Q row-major with 1/16 pre-applied.
__global__ __launch_bounds__(128)
void convert_qkv(const float* __restrict__ Q, const float* __restrict__ K,
                 const float* __restrict__ V, unsigned char* __restrict__ ws) {
  const int t = blockIdx.x;  // b*64 + tix  (32-row groups)
  const int b = t >> 6, tix = t & 63;
  const float* qt = Q + ((size_t)b * NL + tix * KVB) * ND;
  const float* kt = K + ((size_t)b * NL + tix * KVB) * ND;
  const float* vt = V + ((size_t)b * NL + tix * KVB) * ND;
  unsigned char* qd = ws + WS_Q + (size_t)t * TILE_BYTES;
  unsigned char* kd = ws + WS_K + (size_t)t * TILE_BYTES;
  unsigned char* vd = ws + WS_V + (size_t)t * TILE_BYTES;
#pragma unroll
  for (int it = 0; it < 8; ++it) {
    int idx = it * 128 + threadIdx.x;
    int row = idx >> 5, u = idx & 31, f = u * 8;
    const float4* qp = (const float4*)(qt + (size_t)row * ND + f);
    *(short8*)(qd + (row * 512 + f * 2)) = cvt8(qp[0], qp[1], 0.0625f);
    const float4* kp = (const float4*)(kt + (size_t)row * ND + f);
    int kb = (row * 512 + f * 2) ^ ((row & 7) << 4);
    *(short8*)(kd + kb) = cvt8(kp[0], kp[1], 1.0f);
    const float4* vp = (const float4*)(vt + (size_t)row * ND + f);
    int vb = (row >> 2) * 2048 + (u >> 1) * 128 + (row & 3) * 32 + (u & 1) * 16;
    *(short8*)(vd + vb) = cvt8(vp[0], vp[1], 1.0f);
  }
}

// Flash attention fwd (r7 structure): block = (b, 64-row q-tile, chunk of <=8
// kv tiles), 4 waves. K double-buffered, V single-buffered (53 KB LDS -> 3
// blocks/CU), 2 barriers/tile. Defer-max (THR=8) skips the O-rescale when no
// row's max grew — exact in the LSE combine. qt=0 spans ALL 64 kv tiles so
// the combine reproduces the reference's -10000-tier tie semantics exactly.
__global__ __launch_bounds__(256, 3)
void attn_fwd(const int* __restrict__ Mg, unsigned char* ws,
              const int* __restrict__ modeFlag) {
  __shared__ unsigned short Ks[2][KVB * ND];   // 32 KB (also epilogue scratch)
  __shared__ unsigned short Vs[KVB * ND];      // 16 KB single buffer
  __shared__ unsigned short Ps[4][16 * KVB];   // per-wave P (4 KB)
  __shared__ float biasC[CHUNK * KVB];         // whole-chunk padding bias (1 KB)

  const int tid = threadIdx.x;
  const int wv = tid >> 6;      // wave 0..3
  const int lane = tid & 63;
  const int g = lane >> 4;      // 4-lane-group id
  const int cc = lane & 15;     // lane-in-group
  const int maskByteMode = *modeFlag;

  // ---- decode fid -> (b, qt, c)
  const int fid = blockIdx.x;
  const int b = fid / NCHUNKS_B;
  int rem = fid - b * NCHUNKS_B;
  int qt = 0, c = 0, pbase = 0;
  if (rem < 8) {
    qt = 0; c = rem; pbase = 0;
  } else {
    rem -= 8; pbase = 8;
    for (qt = 1; qt < NQT; ++qt) {
      int ncq = (qt >> 2) + 1;
      if (rem < ncq) { c = rem; break; }
      rem -= ncq; pbase += ncq;
    }
  }
  const int qb = qt * QB;
  const int nt_s = (qt == 0) ? NT_ALL : (2 * qt + 2);
  const int t0 = c * CHUNK;
  const int t1 = min(nt_s, t0 + CHUNK);
  unsigned char* pp = ws + WS_P + (size_t)(b * NCHUNKS_B + pbase + c) * PART_BYTES;
  unsigned short* ppA = (unsigned short*)pp;
  float* ppM = (float*)(pp + QB * ND * 2);
  float* ppL = ppM + QB;

  auto stage_K = [&](int tix, int bi) {
    const unsigned char* kg = ws + WS_K + ((size_t)(b * NT_ALL + tix)) * TILE_BYTES;
#pragma unroll
    for (int s = 0; s < 4; ++s) {
      const int seg = wv * 4 + s;  // wave-uniform LDS dest; per-lane global src
      __builtin_amdgcn_global_load_lds(
          (const __attribute__((address_space(1))) unsigned int*)(kg + seg * 1024 + lane * 16),
          (__attribute__((address_space(3))) unsigned int*)((unsigned char*)&Ks[bi][0] + seg * 1024),
          16, 0, 0);
    }
  };
  auto stage_V = [&](int tix) {
    const unsigned char* vg = ws + WS_V + ((size_t)(b * NT_ALL + tix)) * TILE_BYTES;
#pragma unroll
    for (int s = 0; s < 4; ++s) {
      const int seg = wv * 4 + s;
      __builtin_amdgcn_global_load_lds(
          (const __attribute__((address_space(1))) unsigned int*)(vg + seg * 1024 + lane * 16),
          (__attribute__((address_space(3))) unsigned int*)((unsigned char*)&Vs[0] + seg * 1024),
          16, 0, 0);
    }
  };

  // ---- hoist padding-mask bias for the whole chunk out of the tile chain
  {
    int nb = (t1 - t0) * KVB;
    for (int i = tid; i < nb; i += 256) {
      size_t gi = (size_t)b * NL + t0 * KVB + i;
      int mv = maskByteMode ? (int)((const unsigned char*)Mg)[gi] : Mg[gi];
      biasC[i] = mv ? 0.f : -10000.f;
    }
  }

  // ---- Q fragments from bf16 image (1/16 pre-applied): row qb+16wv+cc
  const unsigned char* qrow = ws + WS_Q + ((size_t)b * NL + (qb + 16 * wv + cc)) * 512;
  short8 qf[8];
#pragma unroll
  for (int ch = 0; ch < 8; ++ch) {
    qf[ch] = *(const short8*)(qrow + ch * 64 + g * 16);
  }

  f32x4 acc[16];
#pragma unroll
  for (int i = 0; i < 16; ++i) acc[i] = (f32x4){0.f, 0.f, 0.f, 0.f};
  float m_run[4], l_run[4];
#pragma unroll
  for (int r = 0; r < 4; ++r) { m_run[r] = -3.0e38f; l_run[r] = 0.f; }

  int cur = 0;
  stage_K(t0, 0);
  stage_V(t0);
  __syncthreads();  // drains K(t0)+V(t0) DMA + biasC writes

  for (int tix = t0; tix < t1; ++tix) {
    if (tix + 1 < t1) stage_K(tix + 1, cur ^ 1);  // K DMA under this compute
    const int kv0 = tix * KVB;
    const float* biasT = &biasC[(tix - t0) * KVB];

    // ---- S = Q K^T (two 16-col kv tiles)
    const char* ksB = (const char*)&Ks[cur][0];
    f32x4 s0 = {0.f, 0.f, 0.f, 0.f}, s1 = {0.f, 0.f, 0.f, 0.f};
#pragma unroll
    for (int ch = 0; ch < 8; ++ch) {
      int cbase = ch * 64 + g * 16;
      int b0 = (cc * 512 + cbase) ^ ((cc & 7) << 4);
      int b1 = ((cc + 16) * 512 + cbase) ^ ((cc & 7) << 4);
      short8 k0 = *reinterpret_cast<const short8*>(ksB + b0);
      short8 k1 = *reinterpret_cast<const short8*>(ksB + b1);
      s0 = __builtin_amdgcn_mfma_f32_16x16x32_bf16(qf[ch], k0, s0, 0, 0, 0);
      s1 = __builtin_amdgcn_mfma_f32_16x16x32_bf16(qf[ch], k1, s1, 0, 0, 0);
    }
    // ---- biases: padding (all rows), causal (diagonal tiles and beyond)
    float bi0 = biasT[cc], bi1 = biasT[16 + cc];
    s0 += bi0;
    s1 += bi1;
    if (kv0 + KVB - 1 > qb) {
      int kvg0 = kv0 + cc, kvg1 = kv0 + 16 + cc;
      int qg = qb + 16 * wv + 4 * g;
#pragma unroll
      for (int r = 0; r < 4; ++r) {
        if (kvg0 > qg + r) s0[r] -= 10000.f;
        if (kvg1 > qg + r) s1[r] -= 10000.f;
      }
    }
    // ---- online softmax with defer-max (row 4g+r lives in 16 lanes sharing g)
    float rmax[4], rsum[4];
#pragma unroll
    for (int r = 0; r < 4; ++r) rmax[r] = fmaxf(s0[r], s1[r]);
#pragma unroll
    for (int off = 8; off >= 1; off >>= 1) {
#pragma unroll
      for (int r = 0; r < 4; ++r) rmax[r] = fmaxf(rmax[r], __shfl_xor(rmax[r], off));
    }
    bool grow = (rmax[0] > m_run[0] + 8.f) || (rmax[1] > m_run[1] + 8.f) ||
                (rmax[2] > m_run[2] + 8.f) || (rmax[3] > m_run[3] + 8.f);
    if (__any(grow)) {   // wave-uniform; exact in the LSE combine (m-hat cancels)
      f32x4 av;
#pragma unroll
      for (int r = 0; r < 4; ++r) {
        float mn = fmaxf(m_run[r], rmax[r]);
        float alpha = __expf(m_run[r] - mn);
        m_run[r] = mn;
        l_run[r] *= alpha;
        av[r] = alpha;
      }
#pragma unroll
      for (int i = 0; i < 16; ++i) acc[i] *= av;
    }
#pragma unroll
    for (int r = 0; r < 4; ++r) {
      s0[r] = __expf(s0[r] - m_run[r]);
      s1[r] = __expf(s1[r] - m_run[r]);
      rsum[r] = s0[r] + s1[r];
    }
#pragma unroll
    for (int off = 8; off >= 1; off >>= 1) {
#pragma unroll
      for (int r = 0; r < 4; ++r) rsum[r] += __shfl_xor(rsum[r], off);
    }
#pragma unroll
    for (int r = 0; r < 4; ++r) l_run[r] += rsum[r];

    // ---- P -> per-wave LDS so PV's A-operand reads contiguous kv
    unsigned short* pw = &Ps[wv][0];
#pragma unroll
    for (int r = 0; r < 4; ++r) {
      pw[(4 * g + r) * KVB + cc] = bf16rne(s0[r]);
      pw[(4 * g + r) * KVB + 16 + cc] = bf16rne(s1[r]);
    }
    asm volatile("s_waitcnt lgkmcnt(0)" ::: "memory");
    short8 pa = *reinterpret_cast<const short8*>((const char*)pw + cc * 64 + g * 16);

    __syncthreads();  // #1: publish V(tix) DMA to all waves (drains vmcnt)

    // ---- O += P V via hardware transpose reads (8 B/lane natural addressing)
    const unsigned va = (unsigned)(uintptr_t)&Vs[0] + g * 4096 + cc * 8;
#pragma unroll
    for (int h8 = 0; h8 < 2; ++h8) {
      short4v lo[8], hi[8];
#pragma unroll
      for (int f8 = 0; f8 < 8; ++f8) {
        const int ft = h8 * 8 + f8;
        asm volatile("ds_read_b64_tr_b16 %0, %1 offset:%2"
                     : "=&v"(lo[f8]) : "v"(va), "i"(ft * 128) : "memory");
        asm volatile("ds_read_b64_tr_b16 %0, %1 offset:%2"
                     : "=&v"(hi[f8]) : "v"(va), "i"(ft * 128 + 2048) : "memory");
      }
      asm volatile("s_waitcnt lgkmcnt(0)" ::: "memory");
      __builtin_amdgcn_sched_barrier(0);
#pragma unroll
      for (int f8 = 0; f8 < 8; ++f8) {
        short8 vb = __builtin_shufflevector(lo[f8], hi[f8], 0, 1, 2, 3, 4, 5, 6, 7);
        acc[h8 * 8 + f8] =
            __builtin_amdgcn_mfma_f32_16x16x32_bf16(pa, vb, acc[h8 * 8 + f8], 0, 0, 0);
      }
    }

    __syncthreads();  // #2: all waves done reading Vs (and Ks[cur])
    if (tix + 1 < t1) stage_V(tix + 1);  // V DMA flies under next QK/softmax
    cur ^= 1;
  }

  // ---- partial epilogue: transpose acc through LDS (reuse Ks, 32 KB)
  unsigned short* sc = &Ks[0][0];
#pragma unroll
  for (int ft = 0; ft < 16; ++ft) {
#pragma unroll
    for (int r = 0; r < 4; ++r) {
      sc[(16 * wv + 4 * g + r) * 256 + ft * 16 + cc] = bf16rne(acc[ft][r]);
    }
  }
  if (cc == 0) {
#pragma unroll
    for (int r = 0; r < 4; ++r) {
      int rr = 16 * wv + 4 * g + r;
      ppM[rr] = m_run[r];
      ppL[rr] = l_run[r];
    }
  }
  __syncthreads();
  {
    const int row = tid >> 2, q4 = tid & 3;
    const unsigned short* srow = sc + row * 256 + q4 * 64;
#pragma unroll
    for (int kk = 0; kk < 8; ++kk) {
      *(ushort8*)(ppA + (size_t)row * ND + q4 * 64 + kk * 8) =
          *(const ushort8*)(srow + kk * 8);
    }
  }
}

// Exact log-sum-exp merge of the variable-count partials per (b, q-tile).
__global__ __launch_bounds__(256)
void attn_combine(const unsigned char* __restrict__ ws, float* __restrict__ Og) {
  const int bid = blockIdx.x;  // b*32 + qt
  const int b = bid >> 5, qt = bid & 31;
  const int tid = threadIdx.x;
  const int row = tid >> 2, sub = tid & 3;

  int pbase = 0, nc = 8;
  if (qt > 0) {
    pbase = 8;
    for (int j = 1; j < qt; ++j) pbase += (j >> 2) + 1;
    nc = (qt >> 2) + 1;
  }
  const unsigned char* p0 = ws + WS_P + (size_t)(b * NCHUNKS_B + pbase) * PART_BYTES;

  float M = -3.0e38f;
  for (int c = 0; c < nc; ++c) {
    M = fmaxf(M, *(const float*)(p0 + (size_t)c * PART_BYTES + QB * ND * 2 + row * 4));
  }
  float L = 0.f;
  float o[64];
#pragma unroll
  for (int j = 0; j < 64; ++j) o[j] = 0.f;
  for (int c = 0; c < nc; ++c) {
    const unsigned char* pc = p0 + (size_t)c * PART_BYTES;
    float mm = *(const float*)(pc + QB * ND * 2 + row * 4);
    float ll = *(const float*)(pc + QB * ND * 2 + QB * 4 + row * 4);
    float s = __expf(mm - M);
    L += ll * s;
    const unsigned short* pa =
        (const unsigned short*)pc + (size_t)row * ND + sub * 64;
#pragma unroll
    for (int kk = 0; kk < 8; ++kk) {
      ushort8 a = *(const ushort8*)(pa + kk * 8);
#pragma unroll
      for (int j = 0; j < 8; ++j) {
        unsigned u = ((unsigned)a[j]) << 16;
        o[kk * 8 + j] += __builtin_bit_cast(float, u) * s;
      }
    }
  }
  const float invL = 1.0f / L;
  float* op = Og + ((size_t)b * NL + qt * QB + row) * ND + sub * 64;
#pragma unroll
  for (int kk = 0; kk < 16; ++kk) {
    float4 v = {o[kk * 4] * invL, o[kk * 4 + 1] * invL, o[kk * 4 + 2] * invL,
                o[kk * 4 + 3] * invL};
    *(float4*)(op + kk * 4) = v;
  }
}

extern "C" void kernel_launch(void* const* d_in, const int* in_sizes, int n_in,
                              void* d_out, int out_size, void* d_ws, size_t ws_size,
                              hipStream_t stream) {
  (void)in_sizes; (void)n_in; (void)out_size; (void)ws_size;  // 65.6MB <= 67.6MB proven (r5)
  const float* Q = (const float*)d_in[0];
  const float* K = (const float*)d_in[1];
  const float* V = (const float*)d_in[2];
  const int* M = (const int*)d_in[3];
  unsigned char* ws = (unsigned char*)d_ws;

  mask_mode_kernel<<<dim3(1), dim3(64), 0, stream>>>((const unsigned*)M, (int*)ws);
  convert_qkv<<<dim3(512), dim3(128), 0, stream>>>(Q, K, V, ws);
  attn_fwd<<<dim3(8 * NCHUNKS_B), dim3(256), 0, stream>>>(M, ws, (const int*)ws);
  attn_combine<<<dim3(256), dim3(256), 0, stream>>>(ws, (float*)d_out);
}

// Round 12
// 109.498 us; speedup vs baseline: 2.2966x; 1.2878x over previous
//
#include <hip/hip_runtime.h>
#include <stdint.h>

#define NL 2048
#define ND 256
#define KVB 32
#define QB 64
#define NQT 32                      // 64-row q-tiles per batch
#define NT_ALL (NL / KVB)           // 64 kv tiles per batch
#define CHUNK 10                    // kv tiles per block -> 125 chunks/batch, grid 1000
#define NCHUNKS_B 125               // 7 (qt=0 spans all 64) + sum_{qt=1..31} ceil((2qt+2)/10)
#define TILE_BYTES (KVB * ND * 2)   // 16 KB image per kv tile
#define IMG (8 * NT_ALL * TILE_BYTES)
#define WS_K 256
#define WS_V (WS_K + IMG)
#define WS_P (WS_V + IMG)
#define PART_BYTES (QB * ND * 2 + QB * 8)  // bf16 acc + fp32 m,l = 33280

typedef __attribute__((ext_vector_type(8))) short short8;
typedef __attribute__((ext_vector_type(4))) short short4v;
typedef __attribute__((ext_vector_type(4))) float f32x4;
typedef __attribute__((ext_vector_type(8))) unsigned short ushort8;

__device__ __forceinline__ unsigned short bf16rne(float x) {
  unsigned u = __builtin_bit_cast(unsigned, x);
  u += 0x7FFFu + ((u >> 16) & 1u);
  return (unsigned short)(u >> 16);
}

__device__ __forceinline__ short8 cvt8(float4 a, float4 b, float scale) {
  short8 v;
  v[0] = (short)bf16rne(a.x * scale);
  v[1] = (short)bf16rne(a.y * scale);
  v[2] = (short)bf16rne(a.z * scale);
  v[3] = (short)bf16rne(a.w * scale);
  v[4] = (short)bf16rne(b.x * scale);
  v[5] = (short)bf16rne(b.y * scale);
  v[6] = (short)bf16rne(b.z * scale);
  v[7] = (short)bf16rne(b.w * scale);
  return v;
}

// Mask storage probe: any word not 0/1 in the first 4096 words => byte bools.
__global__ void mask_mode_kernel(const unsigned* __restrict__ M, int* __restrict__ flag) {
  bool bad = false;
  for (int i = threadIdx.x; i < 4096; i += 64) {
    if (M[i] > 1u) bad = true;
  }
  unsigned long long b = __ballot(bad);
  if (threadIdx.x == 0) *flag = (b != 0ULL) ? 1 : 0;
}

// One-shot K,V fp32->bf16 conversion. K stored as XOR-swizzled LDS tile
// images, V in the tr-read subtile layout. (Q is read fp32 directly in fwd —
// once per block, so the image round-trip isn't worth it.)
__global__ __launch_bounds__(128)
void convert_kv(const float* __restrict__ K, const float* __restrict__ V,
                unsigned char* __restrict__ ws) {
  const int t = blockIdx.x;  // b*64 + tix  (32-row tiles)
  const int b = t >> 6, tix = t & 63;
  const float* kt = K + ((size_t)b * NL + tix * KVB) * ND;
  const float* vt = V + ((size_t)b * NL + tix * KVB) * ND;
  unsigned char* kd = ws + WS_K + (size_t)t * TILE_BYTES;
  unsigned char* vd = ws + WS_V + (size_t)t * TILE_BYTES;
#pragma unroll
  for (int it = 0; it < 8; ++it) {
    int idx = it * 128 + threadIdx.x;
    int row = idx >> 5, u = idx & 31, f = u * 8;
    const float4* kp = (const float4*)(kt + (size_t)row * ND + f);
    int kb = (row * 512 + f * 2) ^ ((row & 7) << 4);
    *(short8*)(kd + kb) = cvt8(kp[0], kp[1], 1.0f);
    const float4* vp = (const float4*)(vt + (size_t)row * ND + f);
    int vb = (row >> 2) * 2048 + (u >> 1) * 128 + (row & 3) * 32 + (u & 1) * 16;
    *(short8*)(vd + vb) = cvt8(vp[0], vp[1], 1.0f);
  }
}

// Flash attention fwd (r7 structure): block = (b, 64-row q-tile, chunk of <=10
// kv tiles), 4 waves, K+V double-buffered global_load_lds DMA, 1 barrier/tile.
// Defer-max (THR=8) skips the O-rescale when no row's max grew (exact in the
// LSE combine). qt=0 spans ALL 64 kv tiles so the combine reproduces the
// reference's -10000-tier tie semantics exactly.
__global__ __launch_bounds__(256, 2)
void attn_fwd(const float* __restrict__ Qg, const int* __restrict__ Mg,
              unsigned char* ws, const int* __restrict__ modeFlag) {
  __shared__ unsigned short Ks[2][KVB * ND];   // 32 KB (also epilogue scratch)
  __shared__ unsigned short Vs[2][KVB * ND];   // 32 KB
  __shared__ unsigned short Ps[4][16 * KVB];   // per-wave P (4 KB)
  __shared__ float biasC[CHUNK * KVB];         // whole-chunk padding bias

  const int tid = threadIdx.x;
  const int wv = tid >> 6;      // wave 0..3
  const int lane = tid & 63;
  const int g = lane >> 4;      // 4-lane-group id
  const int cc = lane & 15;     // lane-in-group
  const int maskByteMode = *modeFlag;

  // ---- decode fid -> (b, qt, c)
  const int fid = blockIdx.x;
  const int b = fid / NCHUNKS_B;
  int rem = fid - b * NCHUNKS_B;
  int qt = 0, c = 0, pbase = 0;
  if (rem < 7) {
    qt = 0; c = rem; pbase = 0;
  } else {
    rem -= 7; pbase = 7;
    for (qt = 1; qt < NQT; ++qt) {
      int ncq = (2 * qt + 2 + CHUNK - 1) / CHUNK;
      if (rem < ncq) { c = rem; break; }
      rem -= ncq; pbase += ncq;
    }
  }
  const int qb = qt * QB;
  const int nt_s = (qt == 0) ? NT_ALL : (2 * qt + 2);
  const int t0 = c * CHUNK;
  const int t1 = min(nt_s, t0 + CHUNK);
  unsigned char* pp = ws + WS_P + (size_t)(b * NCHUNKS_B + pbase + c) * PART_BYTES;
  unsigned short* ppA = (unsigned short*)pp;
  float* ppM = (float*)(pp + QB * ND * 2);
  float* ppL = ppM + QB;

  auto stage_tile = [&](int tix, int bi) {
    const unsigned char* kg = ws + WS_K + ((size_t)(b * NT_ALL + tix)) * TILE_BYTES;
    const unsigned char* vg = ws + WS_V + ((size_t)(b * NT_ALL + tix)) * TILE_BYTES;
#pragma unroll
    for (int s = 0; s < 4; ++s) {
      const int seg = wv * 4 + s;  // wave-uniform LDS dest; per-lane global src
      __builtin_amdgcn_global_load_lds(
          (const __attribute__((address_space(1))) unsigned int*)(kg + seg * 1024 + lane * 16),
          (__attribute__((address_space(3))) unsigned int*)((unsigned char*)&Ks[bi][0] + seg * 1024),
          16, 0, 0);
      __builtin_amdgcn_global_load_lds(
          (const __attribute__((address_space(1))) unsigned int*)(vg + seg * 1024 + lane * 16),
          (__attribute__((address_space(3))) unsigned int*)((unsigned char*)&Vs[bi][0] + seg * 1024),
          16, 0, 0);
    }
  };

  // ---- hoist padding-mask bias for the whole chunk out of the tile chain
  {
    int nb = (t1 - t0) * KVB;
    for (int i = tid; i < nb; i += 256) {
      size_t gi = (size_t)b * NL + t0 * KVB + i;
      int mv = maskByteMode ? (int)((const unsigned char*)Mg)[gi] : Mg[gi];
      biasC[i] = mv ? 0.f : -10000.f;
    }
  }

  // ---- Q fragments direct from fp32 (once per block), scaled 1/16
  const float* qp = Qg + ((size_t)b * NL + (qb + 16 * wv + cc)) * ND;
  short8 qf[8];
#pragma unroll
  for (int ch = 0; ch < 8; ++ch) {
    int f = ch * 32 + g * 8;
    float4 a0 = *reinterpret_cast<const float4*>(qp + f);
    float4 a1 = *reinterpret_cast<const float4*>(qp + f + 4);
    qf[ch] = cvt8(a0, a1, 0.0625f);
  }

  f32x4 acc[16];
#pragma unroll
  for (int i = 0; i < 16; ++i) acc[i] = (f32x4){0.f, 0.f, 0.f, 0.f};
  float m_run[4], l_run[4];
#pragma unroll
  for (int r = 0; r < 4; ++r) { m_run[r] = -3.0e38f; l_run[r] = 0.f; }

  int buf = 0;
  stage_tile(t0, 0);
  __syncthreads();  // drains DMA + biasC writes

  for (int tix = t0; tix < t1; ++tix) {
    if (tix + 1 < t1) stage_tile(tix + 1, buf ^ 1);  // DMA under this compute
    const int kv0 = tix * KVB;
    const float* biasT = &biasC[(tix - t0) * KVB];

    // ---- S = Q K^T (two 16-col kv tiles)
    const char* ksB = (const char*)&Ks[buf][0];
    f32x4 s0 = {0.f, 0.f, 0.f, 0.f}, s1 = {0.f, 0.f, 0.f, 0.f};
    __builtin_amdgcn_s_setprio(1);
#pragma unroll
    for (int ch = 0; ch < 8; ++ch) {
      int cbase = ch * 64 + g * 16;
      int b0 = (cc * 512 + cbase) ^ ((cc & 7) << 4);
      int b1 = ((cc + 16) * 512 + cbase) ^ ((cc & 7) << 4);
      short8 k0 = *reinterpret_cast<const short8*>(ksB + b0);
      short8 k1 = *reinterpret_cast<const short8*>(ksB + b1);
      s0 = __builtin_amdgcn_mfma_f32_16x16x32_bf16(qf[ch], k0, s0, 0, 0, 0);
      s1 = __builtin_amdgcn_mfma_f32_16x16x32_bf16(qf[ch], k1, s1, 0, 0, 0);
    }
    __builtin_amdgcn_s_setprio(0);
    // ---- biases: padding (all rows), causal (diagonal tiles and beyond)
    float bi0 = biasT[cc], bi1 = biasT[16 + cc];
    s0 += bi0;
    s1 += bi1;
    if (kv0 + KVB - 1 > qb) {
      int kvg0 = kv0 + cc, kvg1 = kv0 + 16 + cc;
      int qg = qb + 16 * wv + 4 * g;
#pragma unroll
      for (int r = 0; r < 4; ++r) {
        if (kvg0 > qg + r) s0[r] -= 10000.f;
        if (kvg1 > qg + r) s1[r] -= 10000.f;
      }
    }
    // ---- online softmax with defer-max (row 4g+r lives in 16 lanes sharing g)
    float rmax[4], rsum[4];
#pragma unroll
    for (int r = 0; r < 4; ++r) rmax[r] = fmaxf(s0[r], s1[r]);
#pragma unroll
    for (int off = 8; off >= 1; off >>= 1) {
#pragma unroll
      for (int r = 0; r < 4; ++r) rmax[r] = fmaxf(rmax[r], __shfl_xor(rmax[r], off));
    }
    bool grow = (rmax[0] > m_run[0] + 8.f) || (rmax[1] > m_run[1] + 8.f) ||
                (rmax[2] > m_run[2] + 8.f) || (rmax[3] > m_run[3] + 8.f);
    if (__any(grow)) {   // wave-uniform; exact in the LSE combine (m-hat cancels)
      f32x4 av;
#pragma unroll
      for (int r = 0; r < 4; ++r) {
        float mn = fmaxf(m_run[r], rmax[r]);
        float alpha = __expf(m_run[r] - mn);
        m_run[r] = mn;
        l_run[r] *= alpha;
        av[r] = alpha;
      }
#pragma unroll
      for (int i = 0; i < 16; ++i) acc[i] *= av;
    }
#pragma unroll
    for (int r = 0; r < 4; ++r) {
      s0[r] = __expf(s0[r] - m_run[r]);
      s1[r] = __expf(s1[r] - m_run[r]);
      rsum[r] = s0[r] + s1[r];
    }
#pragma unroll
    for (int off = 8; off >= 1; off >>= 1) {
#pragma unroll
      for (int r = 0; r < 4; ++r) rsum[r] += __shfl_xor(rsum[r], off);
    }
#pragma unroll
    for (int r = 0; r < 4; ++r) l_run[r] += rsum[r];

    // ---- P -> per-wave LDS so PV's A-operand reads contiguous kv
    unsigned short* pw = &Ps[wv][0];
#pragma unroll
    for (int r = 0; r < 4; ++r) {
      pw[(4 * g + r) * KVB + cc] = bf16rne(s0[r]);
      pw[(4 * g + r) * KVB + 16 + cc] = bf16rne(s1[r]);
    }
    asm volatile("s_waitcnt lgkmcnt(0)" ::: "memory");
    __builtin_amdgcn_sched_barrier(0);

    // ---- O += P V: P read + ALL 32 tr-reads issued up-front; counted
    // lgkmcnt(15) (HW max) overlaps the first MFMA batch with the 15 still-
    // in-flight tr-reads (DS completes in order: >=18 done covers pa+ft0..7).
    short8 pa;
    {
      const unsigned paddr = (unsigned)(uintptr_t)pw + (unsigned)(cc * 64 + g * 16);
      asm volatile("ds_read_b128 %0, %1" : "=&v"(pa) : "v"(paddr) : "memory");
    }
    const unsigned va = (unsigned)(uintptr_t)&Vs[buf][0] + g * 4096 + cc * 8;
    short4v lo[16], hi[16];
#pragma unroll
    for (int ft = 0; ft < 16; ++ft) {
      asm volatile("ds_read_b64_tr_b16 %0, %1 offset:%2"
                   : "=&v"(lo[ft]) : "v"(va), "i"(ft * 128) : "memory");
      asm volatile("ds_read_b64_tr_b16 %0, %1 offset:%2"
                   : "=&v"(hi[ft]) : "v"(va), "i"(ft * 128 + 2048) : "memory");
    }
    asm volatile("s_waitcnt lgkmcnt(15)" ::: "memory");  // >=18 done: pa + ft 0..7
    __builtin_amdgcn_sched_barrier(0);
    __builtin_amdgcn_s_setprio(1);
#pragma unroll
    for (int ft = 0; ft < 8; ++ft) {
      short8 vb = __builtin_shufflevector(lo[ft], hi[ft], 0, 1, 2, 3, 4, 5, 6, 7);
      acc[ft] = __builtin_amdgcn_mfma_f32_16x16x32_bf16(pa, vb, acc[ft], 0, 0, 0);
    }
    __builtin_amdgcn_s_setprio(0);
    asm volatile("s_waitcnt lgkmcnt(0)" ::: "memory");
    __builtin_amdgcn_sched_barrier(0);
    __builtin_amdgcn_s_setprio(1);
#pragma unroll
    for (int ft = 8; ft < 16; ++ft) {
      short8 vb = __builtin_shufflevector(lo[ft], hi[ft], 0, 1, 2, 3, 4, 5, 6, 7);
      acc[ft] = __builtin_amdgcn_mfma_f32_16x16x32_bf16(pa, vb, acc[ft], 0, 0, 0);
    }
    __builtin_amdgcn_s_setprio(0);

    __syncthreads();  // drains prefetch DMA + releases buf
    buf ^= 1;
  }

  // ---- partial epilogue: transpose acc through LDS (reuse Ks, 32 KB)
  unsigned short* sc = &Ks[0][0];
#pragma unroll
  for (int ft = 0; ft < 16; ++ft) {
#pragma unroll
    for (int r = 0; r < 4; ++r) {
      sc[(16 * wv + 4 * g + r) * 256 + ft * 16 + cc] = bf16rne(acc[ft][r]);
    }
  }
  if (cc == 0) {
#pragma unroll
    for (int r = 0; r < 4; ++r) {
      int rr = 16 * wv + 4 * g + r;
      ppM[rr] = m_run[r];
      ppL[rr] = l_run[r];
    }
  }
  __syncthreads();
  {
    const int row = tid >> 2, q4 = tid & 3;
    const unsigned short* srow = sc + row * 256 + q4 * 64;
#pragma unroll
    for (int kk = 0; kk < 8; ++kk) {
      *(ushort8*)(ppA + (size_t)row * ND + q4 * 64 + kk * 8) =
          *(const ushort8*)(srow + kk * 8);
    }
  }
}

// Exact log-sum-exp merge of the variable-count partials per (b, q-tile).
__global__ __launch_bounds__(256)
void attn_combine(const unsigned char* __restrict__ ws, float* __restrict__ Og) {
  const int bid = blockIdx.x;  // b*32 + qt
  const int b = bid >> 5, qt = bid & 31;
  const int tid = threadIdx.x;
  const int row = tid >> 2, sub = tid & 3;

  int pbase = 0, nc = 7;
  if (qt > 0) {
    pbase = 7;
    for (int j = 1; j < qt; ++j) pbase += (2 * j + 2 + CHUNK - 1) / CHUNK;
    nc = (2 * qt + 2 + CHUNK - 1) / CHUNK;
  }
  const unsigned char* p0 = ws + WS_P + (size_t)(b * NCHUNKS_B + pbase) * PART_BYTES;

  float M = -3.0e38f;
  for (int c = 0; c < nc; ++c) {
    M = fmaxf(M, *(const float*)(p0 + (size_t)c * PART_BYTES + QB * ND * 2 + row * 4));
  }
  float L = 0.f;
  float o[64];
#pragma unroll
  for (int j = 0; j < 64; ++j) o[j] = 0.f;
  for (int c = 0; c < nc; ++c) {
    const unsigned char* pc = p0 + (size_t)c * PART_BYTES;
    float mm = *(const float*)(pc + QB * ND * 2 + row * 4);
    float ll = *(const float*)(pc + QB * ND * 2 + QB * 4 + row * 4);
    float s = __expf(mm - M);
    L += ll * s;
    const unsigned short* pa =
        (const unsigned short*)pc + (size_t)row * ND + sub * 64;
#pragma unroll
    for (int kk = 0; kk < 8; ++kk) {
      ushort8 a = *(const ushort8*)(pa + kk * 8);
#pragma unroll
      for (int j = 0; j < 8; ++j) {
        unsigned u = ((unsigned)a[j]) << 16;
        o[kk * 8 + j] += __builtin_bit_cast(float, u) * s;
      }
    }
  }
  const float invL = 1.0f / L;
  float* op = Og + ((size_t)b * NL + qt * QB + row) * ND + sub * 64;
#pragma unroll
  for (int kk = 0; kk < 16; ++kk) {
    float4 v = {o[kk * 4] * invL, o[kk * 4 + 1] * invL, o[kk * 4 + 2] * invL,
                o[kk * 4 + 3] * invL};
    *(float4*)(op + kk * 4) = v;
  }
}

extern "C" void kernel_launch(void* const* d_in, const int* in_sizes, int n_in,
                              void* d_out, int out_size, void* d_ws, size_t ws_size,
                              hipStream_t stream) {
  (void)in_sizes; (void)n_in; (void)out_size; (void)ws_size;  // 66.9MB <= 67.6MB proven (r5)
  const float* Q = (const float*)d_in[0];
  const float* K = (const float*)d_in[1];
  const float* V = (const float*)d_in[2];
  const int* M = (const int*)d_in[3];
  unsigned char* ws = (unsigned char*)d_ws;

  mask_mode_kernel<<<dim3(1), dim3(64), 0, stream>>>((const unsigned*)M, (int*)ws);
  convert_kv<<<dim3(512), dim3(128), 0, stream>>>(K, V, ws);
  attn_fwd<<<dim3(8 * NCHUNKS_B), dim3(256), 0, stream>>>(Q, M, ws, (const int*)ws);
  attn_combine<<<dim3(256), dim3(256), 0, stream>>>(ws, (float*)d_out);
}